// Round 2
// baseline (971.081 us; speedup 1.0000x reference)
//
#include <hip/hip_runtime.h>
#include <hip/hip_bf16.h>
#include <cstddef>

// Problem constants
#define BATCH 65536
#define HDIM  256
#define NGATE 7
#define BH    ((size_t)BATCH * HDIM)

// Tiling
#define OTILE 16                 // o-range per block (fixed for block lifetime)
#define WAVES 4
#define BPW   16                 // batches per wave per iteration
#define BITER (WAVES * BPW)      // 64 batches per block-iteration
#define NITER 16                 // iterations per block
#define BGRP  (BITER * NITER)    // 1024 batches per block
#define NOT   (HDIM / OTILE)     // 16 o-tiles
#define NBG   (BATCH / BGRP)     // 64 batch groups -> grid = 1024

typedef __bf16 bf16x8 __attribute__((ext_vector_type(8)));
typedef __bf16 bf16x4 __attribute__((ext_vector_type(4)));
typedef float  f32x4  __attribute__((ext_vector_type(4)));

// ---------------------------------------------------------------------------
// Kernel 1: convert W (G*H*H fp32) -> bf16 in workspace, same (g,o,h) layout.
// ---------------------------------------------------------------------------
__global__ void __launch_bounds__(256) cvt_w_kernel(const float* __restrict__ W,
                                                    __bf16* __restrict__ Wb) {
    int i = (blockIdx.x * 256 + threadIdx.x) * 4;
    float4 v = *(const float4*)(W + i);
    bf16x4 r;
    r[0] = (__bf16)v.x; r[1] = (__bf16)v.y; r[2] = (__bf16)v.z; r[3] = (__bf16)v.w;
    *(bf16x4*)(Wb + i) = r;
}

// ---------------------------------------------------------------------------
// Fast device math (bf16-level tolerance)
// ---------------------------------------------------------------------------
__device__ __forceinline__ float sigmoidf_(float x) {
    return __builtin_amdgcn_rcpf(1.0f + __expf(-x));
}
__device__ __forceinline__ float tanhf_(float x) {
    return 1.0f - 2.0f * __builtin_amdgcn_rcpf(1.0f + __expf(2.0f * x));
}
__device__ __forceinline__ float softplusf_(float x) {
    return fmaxf(x, 0.0f) + __logf(1.0f + __expf(-fabsf(x)));
}

// ---------------------------------------------------------------------------
// Kernel 2: W-resident-in-LDS fused GEMM + CT-LSTM epilogue.
//
// Block = 4 waves, owns o-tile [o0, o0+16) x all 7 gates x full K=256.
// W tile (57344 B) is staged into LDS ONCE (XOR-swizzled), then the block
// streams 1024 batches with NO barriers: MFMA A-operands are ds_read_b128
// (lgkmcnt-scheduled, decoupled from the vmem FIFO); the vmem FIFO carries
// only the h/c_ti/cbar streams and the output stores. Next iteration's h row
// is prefetched into registers under the current MFMAs.
//
// MFMA roles: A = W[g] (M = o), B = h (N = batch).
//   A[m][k]: m = lane&15 (o), k = quad*8+j  -> LDS, swizzled
//   B[k][n]: n = lane&15 (batch)            -> registers, cvt'd once per row
//   C: col = batch, row = o = quad*4+reg    -> float4 epilogue I/O
//
// LDS swizzle: byte = (g*16+o)*512 + (koff ^ ((o&7)<<4)).  Rows are 512 B
// (same banks); XOR spreads the 16 rows over 8 16-B slots -> uniform 8-lane
// occupancy per slot for ds_read_b128 (the b128 minimum), vs 16-way unswizzled.
//
// Grid order: bid = bg*16 + ot, so the 16 blocks sharing a batch-group (same
// h rows) are adjacent -> spread round-robin over the 8 XCDs concurrently,
// h re-reads served by L3/L2.
// LDS 57 KB -> 2 blocks/CU (8 waves/CU).
// ---------------------------------------------------------------------------
__global__ void __launch_bounds__(256, 2)
fused_ctlstm(const float* __restrict__ inter_times,
             const float* __restrict__ h_ti,
             const float* __restrict__ c_ti,
             const float* __restrict__ cbar,
             const __bf16* __restrict__ Wb,
             const float* __restrict__ bias,
             float* __restrict__ out) {
    __shared__ __bf16 wlds[NGATE * OTILE * HDIM];   // 57344 B

    const int tid  = threadIdx.x;
    const int lane = tid & 63;
    const int wave = tid >> 6;
    const int col  = lane & 15;
    const int quad = lane >> 4;

    const int ot = blockIdx.x & (NOT - 1);
    const int bg = blockIdx.x / NOT;
    const int o0 = ot * OTILE;

    // ---- one-time stage of the block's W tile into LDS (swizzled) ----
    // 7*16*256 bf16 = 3584 16-B vectors; 14 per thread.
#pragma unroll
    for (int r = 0; r < 14; ++r) {
        int idx = r * 256 + tid;
        int g   = idx >> 9;          // / 512 vecs per gate
        int rem = idx & 511;
        int o   = rem >> 5;          // 32 vecs per row
        int kv  = rem & 31;
        bf16x8 v = *(const bf16x8*)(Wb + ((size_t)g * HDIM + o0 + o) * HDIM + kv * 8);
        int byte = (g * OTILE + o) * (HDIM * 2) + ((kv * 16) ^ ((o & 7) << 4));
        *(bf16x8*)((char*)wlds + byte) = v;
    }

    // Bias folded into accumulator init (loop-invariant per lane)
    const int orow = o0 + quad * 4;
    f32x4 bv4[NGATE];
#pragma unroll
    for (int g = 0; g < NGATE; ++g)
        bv4[g] = *(const f32x4*)(bias + g * HDIM + orow);

    __syncthreads();                 // the ONLY barrier

    const int   swz  = (col & 7) << 4;
    const char* wrow = (const char*)wlds + col * (HDIM * 2);

    int b = bg * BGRP + wave * BPW + col;

    // Prefetch h row for it = 0
    float4 hv[16];
    {
        const float* hp = h_ti + (size_t)b * HDIM + quad * 8;
#pragma unroll
        for (int ks = 0; ks < 8; ++ks) {
            hv[2 * ks]     = *(const float4*)(hp + ks * 32);
            hv[2 * ks + 1] = *(const float4*)(hp + ks * 32 + 4);
        }
    }

#pragma unroll 1
    for (int it = 0; it < NITER; ++it) {
        // Convert prefetched h row to bf16 B-fragments (vmcnt wait lands here)
        bf16x8 bfrag[8];
#pragma unroll
        for (int ks = 0; ks < 8; ++ks) {
            float4 lo = hv[2 * ks], hi = hv[2 * ks + 1];
            bf16x8 v;
            v[0] = (__bf16)lo.x; v[1] = (__bf16)lo.y;
            v[2] = (__bf16)lo.z; v[3] = (__bf16)lo.w;
            v[4] = (__bf16)hi.x; v[5] = (__bf16)hi.y;
            v[6] = (__bf16)hi.z; v[7] = (__bf16)hi.w;
            bfrag[ks] = v;
        }

        // Epilogue streams for this iteration (issued before next-h prefetch
        // so their FIFO position is older -> epilogue wait leaves h in flight)
        const size_t idx = (size_t)b * HDIM + orow;
        const f32x4 ct4 = *(const f32x4*)(c_ti + idx);
        const f32x4 cb4 = *(const f32x4*)(cbar + idx);
        const float dt  = inter_times[b];

        // Prefetch next iteration's h row under the MFMAs
        if (it + 1 < NITER) {
            const float* hp = h_ti + (size_t)(b + BITER) * HDIM + quad * 8;
#pragma unroll
            for (int ks = 0; ks < 8; ++ks) {
                hv[2 * ks]     = *(const float4*)(hp + ks * 32);
                hv[2 * ks + 1] = *(const float4*)(hp + ks * 32 + 4);
            }
        }

        f32x4 acc[NGATE];
#pragma unroll
        for (int g = 0; g < NGATE; ++g) acc[g] = bv4[g];

        // MFMA loop: A from LDS (lgkmcnt only), B from registers
#pragma unroll
        for (int ks = 0; ks < 8; ++ks) {
            const int ko = (((ks * 4 + quad) * 16) ^ swz);
#pragma unroll
            for (int g = 0; g < NGATE; ++g) {
                bf16x8 afrag = *(const bf16x8*)(wrow + g * (OTILE * HDIM * 2) + ko);
                acc[g] = __builtin_amdgcn_mfma_f32_16x16x32_bf16(
                    afrag, bfrag[ks], acc[g], 0, 0, 0);
            }
        }

        // Epilogue: per lane, 4 consecutive o for one batch -> float4 I/O
        f32x4 og4, hn4, cn4, cbn4, dec4;
#pragma unroll
        for (int r = 0; r < 4; ++r) {
            const float i_g  = sigmoidf_(acc[0][r]);
            const float f_g  = sigmoidf_(acc[1][r]);
            const float o_g  = sigmoidf_(acc[2][r]);
            const float ib_g = sigmoidf_(acc[3][r]);
            const float fb_g = sigmoidf_(acc[4][r]);
            const float z    = tanhf_(acc[5][r]);
            const float dec  = softplusf_(acc[6][r]);

            const float ct = ct4[r];
            const float cb = cb4[r];

            const float c_after = cb + (ct - cb) * __expf(-dec * dt);
            og4[r]  = o_g;
            hn4[r]  = o_g * tanhf_(c_after);
            cn4[r]  = f_g * c_after + i_g * z;
            cbn4[r] = fb_g * cb + ib_g * z;
            dec4[r] = dec;
        }

        __builtin_nontemporal_store(og4,  (f32x4*)(out + idx));
        __builtin_nontemporal_store(hn4,  (f32x4*)(out + BH + idx));
        __builtin_nontemporal_store(cn4,  (f32x4*)(out + 2 * BH + idx));
        __builtin_nontemporal_store(cbn4, (f32x4*)(out + 3 * BH + idx));
        __builtin_nontemporal_store(dec4, (f32x4*)(out + 4 * BH + idx));

        b += BITER;
    }
}

// ---------------------------------------------------------------------------
extern "C" void kernel_launch(void* const* d_in, const int* in_sizes, int n_in,
                              void* d_out, int out_size, void* d_ws, size_t ws_size,
                              hipStream_t stream) {
    const float* inter_times = (const float*)d_in[0];
    const float* h_ti        = (const float*)d_in[1];
    const float* c_ti        = (const float*)d_in[2];
    const float* cbar        = (const float*)d_in[3];
    const float* W           = (const float*)d_in[4];
    const float* bias        = (const float*)d_in[5];
    float* out = (float*)d_out;

    __bf16* Wb = (__bf16*)d_ws;  // needs G*H*H*2 = 917504 bytes

    cvt_w_kernel<<<(NGATE * HDIM * HDIM) / (256 * 4), 256, 0, stream>>>(W, Wb);

    fused_ctlstm<<<NOT * NBG, 256, 0, stream>>>(inter_times, h_ti, c_ti, cbar,
                                                Wb, bias, out);
}